// Round 5
// baseline (737.446 us; speedup 1.0000x reference)
//
#include <hip/hip_runtime.h>
#include <hip/hip_cooperative_groups.h>
#include <hip/hip_bf16.h>
#include <math.h>

namespace cg = cooperative_groups;

#define N_NODES  50000
#define N_EDGES  800000
#define IN_DIM   128
#define HID      256
#define FC1      1024
#define FC2      512
#define N_ACT    16
#define N_AGENTS 8192

#define BK       64
#define BM       128
#define BN       128

#define EB_STRIDE    64        // max deg per claimed node (Binomial(800k,1/50k)~Poisson-16)

#define SCAT_CHUNK   2048
#define SCAT_BLOCKS  ((N_EDGES + SCAT_CHUNK - 1) / SCAT_CHUNK)   // 391
#define N_BUCKETS    196       // ceil(50000/256): 256-node ranges
#define BUCKET_CAP   4608      // mean 4082, std ~64 -> 8 sigma headroom
#define WTR_BLOCKS   208
#define CLAIM_BLOCKS (N_AGENTS / 256)   // 32

#define GRID_A   1024          // graphc_k: 4 blocks/CU co-resident
#define GRID_B   512           // mlpc_k:   2 blocks/CU co-resident

typedef short bf16x8 __attribute__((ext_vector_type(8)));
typedef float floatx4 __attribute__((ext_vector_type(4)));

__device__ __forceinline__ unsigned short f2b(float f) {
    union { float f; unsigned int i; } v;
    v.f = f;
    unsigned int lsb = (v.i >> 16) & 1u;
    v.i += 0x7fffu + lsb;            // round-to-nearest-even
    return (unsigned short)(v.i >> 16);
}

__device__ __forceinline__ float b2f(unsigned short u) {
    union { unsigned int i; float f; } v;
    v.i = ((unsigned int)u) << 16;
    return v.f;
}

// async global->LDS, 16B per lane. LDS dest = wave-uniform base + lane*16 (linear).
__device__ __forceinline__ void gl_lds(const unsigned short* g, unsigned short* l) {
    __builtin_amdgcn_global_load_lds(
        (const __attribute__((address_space(1))) void*)g,
        (__attribute__((address_space(3))) void*)l, 16, 0, 0);
}

// ======================= shared phase bodies =======================

// ---- weight transpose tile (f32 [K,N] -> bf16 [N,K], 64x64 via LDS) ----
__device__ __forceinline__ void wtr_block(int b, int tid,
    const float* __restrict__ Wgcn, const float* __restrict__ W1,
    const float* __restrict__ W2, const float* __restrict__ Wmu,
    unsigned short* __restrict__ wgcn_t, unsigned short* __restrict__ w1_t,
    unsigned short* __restrict__ w2_t, unsigned short* __restrict__ wmu_t,
    unsigned short (*Ts)[72]) {
    const float* src; unsigned short* dstw; int K, N, tk, tn;
    if (b < 8)        { src = Wgcn; dstw = wgcn_t; K = IN_DIM; N = HID;  tk = b >> 2;        tn = b & 3; }
    else if (b < 72)  { int bb = b - 8;  src = W1; dstw = w1_t; K = HID;  N = FC1;  tk = bb >> 4; tn = bb & 15; }
    else if (b < 200) { int bb = b - 72; src = W2; dstw = w2_t; K = FC1;  N = FC2;  tk = bb >> 3; tn = bb & 7; }
    else              { int bb = b - 200; src = Wmu; dstw = wmu_t; K = FC2; N = N_ACT; tk = bb;   tn = 0; }
    int k0 = tk * 64, n0 = tn * 64;
    int r = tid >> 2;
    int cc = (tid & 3) * 16;
    if (n0 + cc < N) {
        const float* p = src + (size_t)(k0 + r) * N + n0 + cc;
        #pragma unroll
        for (int i = 0; i < 16; i += 4) {
            float4 v = *(const float4*)(p + i);
            Ts[r][cc + i + 0] = f2b(v.x);
            Ts[r][cc + i + 1] = f2b(v.y);
            Ts[r][cc + i + 2] = f2b(v.z);
            Ts[r][cc + i + 3] = f2b(v.w);
        }
    }
    __syncthreads();
    int n = tid >> 2;
    if (n0 + n < N) {
        bf16x8 o0, o1;
        #pragma unroll
        for (int i = 0; i < 8; ++i) o0[i] = (short)Ts[cc + i][n];
        #pragma unroll
        for (int i = 0; i < 8; ++i) o1[i] = (short)Ts[cc + 8 + i][n];
        unsigned short* q = dstw + (size_t)(n0 + n) * K + k0 + cc;
        *(bf16x8*)q = o0;
        *(bf16x8*)(q + 8) = o1;
    }
}

// ---- scatter 2048 edges into 256-node-range buckets (LDS hist + 1 atomic/bucket) ----
__device__ __forceinline__ void scat_body(int blk, int tid,
    const int* __restrict__ src, const int* __restrict__ dst,
    int* __restrict__ bcnt, unsigned long long* __restrict__ pairbuf,
    int* hist, int* base_, int* cur) {
    if (tid < N_BUCKETS) { hist[tid] = 0; cur[tid] = 0; }
    __syncthreads();
    int e0 = blk * SCAT_CHUNK;
    int dv[8];
    #pragma unroll
    for (int i = 0; i < 8; ++i) {
        int e = e0 + i * 256 + tid;
        dv[i] = (e < N_EDGES) ? dst[e] : -1;
        if (dv[i] >= 0) atomicAdd(&hist[dv[i] >> 8], 1);
    }
    __syncthreads();
    if (tid < N_BUCKETS && hist[tid] > 0)
        base_[tid] = atomicAdd(&bcnt[tid], hist[tid]);   // one global atomic per bucket per block
    __syncthreads();
    #pragma unroll
    for (int i = 0; i < 8; ++i) {
        int e = e0 + i * 256 + tid;
        if (e < N_EDGES) {
            int d = dv[i];
            int bk = d >> 8;
            int p = base_[bk] + atomicAdd(&cur[bk], 1);
            if (p < BUCKET_CAP)
                pairbuf[(size_t)bk * BUCKET_CAP + p] =
                    ((unsigned long long)(unsigned)src[e] << 32) | (unsigned)d;
        }
    }
}

// ---- per-bucket: exact deg (LDS hist) + claimed ebuf fill ----
__device__ __forceinline__ void bucket_body(int b, int tid,
    const int* __restrict__ bcnt, const unsigned long long* __restrict__ pairbuf,
    const int* __restrict__ nid, int* __restrict__ deg, int* __restrict__ ebuf,
    int* nidl, int* lhist, int* lfill) {
    int node = b * 256 + tid;
    nidl[tid] = (node < N_NODES) ? nid[node] : 0;
    lhist[tid] = 0;
    lfill[tid] = 0;
    __syncthreads();
    int n = bcnt[b];
    if (n > BUCKET_CAP) n = BUCKET_CAP;
    const unsigned long long* pb = pairbuf + (size_t)b * BUCKET_CAP;
    for (int i = tid; i < n; i += 256) {
        unsigned long long pr = pb[i];
        int d = (int)(unsigned)pr;          // low 32 = dst
        int s = (int)(pr >> 32);            // high 32 = src
        int l = d & 255;
        atomicAdd(&lhist[l], 1);
        int cc = nidl[l];
        if (cc != 0) {
            int p = atomicAdd(&lfill[l], 1);
            if (p < EB_STRIDE) ebuf[((cc - 1) << 6) + p] = s;
        }
    }
    __syncthreads();
    if (node < N_NODES) deg[node] = lhist[tid];   // full overwrite -> no memset needed
}

// ---- aggregate raw x for one agent slot (one wave), shfl-broadcast ----
__device__ __forceinline__ void accumx_row(int c, int lane,
    const int* __restrict__ agent_idx, const int* __restrict__ nid,
    const int* __restrict__ deg, const int* __restrict__ ebuf,
    const float* __restrict__ x, unsigned short* __restrict__ agg) {
    int n = agent_idx[c];
    float ax = 0.0f, ay = 0.0f;
    if (nid[n] == c + 1) {
        int dn_i = deg[n];
        int cnt = dn_i < EB_STRIDE ? dn_i : EB_STRIDE;
        float dn = rsqrtf((float)(dn_i + 1));
        const int* eb = ebuf + (c << 6);
        int ej = (lane < cnt) ? eb[lane] : n;          // coalesced neighbor list
        float wl = rsqrtf((float)(deg[ej] + 1)) * dn;  // per-lane weight, gather once
        for (int i = 0; i < cnt; ++i) {
            int s = __shfl(ej, i);
            float w = __shfl(wl, i);
            float2 u = *(const float2*)(x + (size_t)s * IN_DIM + lane * 2);
            ax += w * u.x;
            ay += w * u.y;
        }
        float2 u = *(const float2*)(x + (size_t)n * IN_DIM + lane * 2);
        float w2 = dn * dn;
        ax += w2 * u.x;
        ay += w2 * u.y;
    }
    unsigned int pk = (unsigned int)f2b(ax) | ((unsigned int)f2b(ay) << 16);
    *(unsigned int*)(agg + (size_t)c * IN_DIM + lane * 2) = pk;
}

// ==== GEMM bodies: global_load_lds staging, linear LDS + XOR swizzle ====
// write: lane L stages global 16B-chunk ((L&7)^(L>>3)) of row (..+L>>3)
// read:  fragment col (ushorts) = (h*32 + quad*8) ^ ((r16&7)<<3)  -> conflict-free

// ---- GCN: 64x128 tile, K=128, bf16(relu(v+bias)) ----
__device__ __forceinline__ void gcn_body(int bid, int tid,
    const unsigned short* __restrict__ A, const unsigned short* __restrict__ Bt,
    const float* __restrict__ bias, unsigned short* __restrict__ outb,
    unsigned short (*As)[64], unsigned short (*Bs)[64]) {
    int tn = (bid >> 3) & 1;
    int tm = (bid & 7) + 8 * (bid >> 4);   // same-tm blocks share an XCD
    int lane = tid & 63, wave = tid >> 6;
    int r16 = lane & 15, quad = lane >> 4;
    int lr = (tid >> 3) & 7;
    int swz = ((tid & 7) ^ lr) * 8;
    const int K = IN_DIM, N = HID;

    floatx4 acc[4][2];
    #pragma unroll
    for (int i = 0; i < 4; ++i)
        #pragma unroll
        for (int j = 0; j < 2; ++j)
            acc[i][j] = (floatx4){0.0f, 0.0f, 0.0f, 0.0f};

    for (int k0 = 0; k0 < K; k0 += BK) {
        if (k0) __syncthreads();
        #pragma unroll
        for (int q = 0; q < 2; ++q)
            gl_lds(A + (size_t)(tm * 64 + (wave * 2 + q) * 8 + lr) * K + k0 + swz,
                   &As[(wave * 2 + q) * 8][0]);
        #pragma unroll
        for (int q = 0; q < 4; ++q)
            gl_lds(Bt + (size_t)(tn * 128 + (wave * 4 + q) * 8 + lr) * K + k0 + swz,
                   &Bs[(wave * 4 + q) * 8][0]);
        __syncthreads();
        #pragma unroll
        for (int h = 0; h < 2; ++h) {
            int col = (h * 32 + quad * 8) ^ ((r16 & 7) << 3);
            bf16x8 af[4], bfr[2];
            #pragma unroll
            for (int i = 0; i < 4; ++i)
                af[i] = *(const bf16x8*)&As[i * 16 + r16][col];
            #pragma unroll
            for (int j = 0; j < 2; ++j)
                bfr[j] = *(const bf16x8*)&Bs[wave * 32 + j * 16 + r16][col];
            #pragma unroll
            for (int i = 0; i < 4; ++i)
                #pragma unroll
                for (int j = 0; j < 2; ++j)
                    acc[i][j] = __builtin_amdgcn_mfma_f32_16x16x32_bf16(af[i], bfr[j], acc[i][j], 0, 0, 0);
        }
    }
    __syncthreads();

    #pragma unroll
    for (int j = 0; j < 2; ++j) {
        int ocol = tn * 128 + wave * 32 + j * 16 + r16;
        float bv = bias[ocol];
        #pragma unroll
        for (int i = 0; i < 4; ++i) {
            int orow = tm * 64 + i * 16 + quad * 4;
            #pragma unroll
            for (int r = 0; r < 4; ++r) {
                float v = acc[i][j][r] + bv;
                if (v < 0.0f) v = 0.0f;
                outb[(size_t)(orow + r) * N + ocol] = f2b(v);
            }
        }
    }
}

// ---- FC1: 128x128 gather GEMM, K=256 ----
__device__ __forceinline__ void fc1_body(int bid, int tid,
    const unsigned short* __restrict__ h_node, const int* __restrict__ agent,
    const int* __restrict__ nid, const unsigned short* __restrict__ Bt,
    const float* __restrict__ bias, unsigned short* __restrict__ outb,
    unsigned short (*As)[64], unsigned short (*Bs)[64]) {
    int tn = (bid >> 3) & 7;
    int tm = (bid & 7) + 8 * (bid >> 6);   // same-tm blocks share an XCD
    int lane = tid & 63, wave = tid >> 6;
    int wm = wave >> 1, wn = wave & 1;
    int r16 = lane & 15, quad = lane >> 4;
    int lr = (tid >> 3) & 7;
    int swz = ((tid & 7) ^ lr) * 8;
    const int K = HID, N = FC1;

    int cA[4];
    #pragma unroll
    for (int q = 0; q < 4; ++q)
        cA[q] = nid[agent[tm * BM + (wave * 4 + q) * 8 + lr]] - 1;

    floatx4 acc[4][4];
    #pragma unroll
    for (int i = 0; i < 4; ++i)
        #pragma unroll
        for (int j = 0; j < 4; ++j)
            acc[i][j] = (floatx4){0.0f, 0.0f, 0.0f, 0.0f};

    for (int k0 = 0; k0 < K; k0 += BK) {
        if (k0) __syncthreads();
        #pragma unroll
        for (int q = 0; q < 4; ++q) {
            gl_lds(h_node + (size_t)cA[q] * K + k0 + swz,
                   &As[(wave * 4 + q) * 8][0]);
            gl_lds(Bt + (size_t)(tn * BN + (wave * 4 + q) * 8 + lr) * K + k0 + swz,
                   &Bs[(wave * 4 + q) * 8][0]);
        }
        __syncthreads();
        #pragma unroll
        for (int h = 0; h < 2; ++h) {
            int col = (h * 32 + quad * 8) ^ ((r16 & 7) << 3);
            bf16x8 af[4], bfr[4];
            #pragma unroll
            for (int i = 0; i < 4; ++i)
                af[i] = *(const bf16x8*)&As[wm * 64 + i * 16 + r16][col];
            #pragma unroll
            for (int j = 0; j < 4; ++j)
                bfr[j] = *(const bf16x8*)&Bs[wn * 64 + j * 16 + r16][col];
            #pragma unroll
            for (int i = 0; i < 4; ++i)
                #pragma unroll
                for (int j = 0; j < 4; ++j)
                    acc[i][j] = __builtin_amdgcn_mfma_f32_16x16x32_bf16(af[i], bfr[j], acc[i][j], 0, 0, 0);
        }
    }
    __syncthreads();

    float bvj[4];
    #pragma unroll
    for (int j = 0; j < 4; ++j) bvj[j] = bias[tn * BN + wn * 64 + j * 16 + r16];

    #pragma unroll
    for (int i = 0; i < 4; ++i) {
        #pragma unroll
        for (int r = 0; r < 4; ++r) {
            int orow = tm * BM + wm * 64 + i * 16 + quad * 4 + r;
            #pragma unroll
            for (int j = 0; j < 4; ++j) {
                int ocol = tn * BN + wn * 64 + j * 16 + r16;
                outb[(size_t)orow * N + ocol] = f2b(acc[i][j][r] + bvj[j]);
            }
        }
    }
}

// ---- LN1 for one row (wave-wide), stats in-register ----
__device__ __forceinline__ void ln1_row(int row, int lane,
    const unsigned short* __restrict__ zb, const float* __restrict__ g1,
    const float* __restrict__ be1, unsigned short* __restrict__ zbn) {
    const unsigned short* p = zb + (size_t)row * FC1 + lane * 16;
    bf16x8 a0 = *(const bf16x8*)p;
    bf16x8 a1 = *(const bf16x8*)(p + 8);
    float v[16];
    #pragma unroll
    for (int i = 0; i < 8; ++i) {
        v[i]     = b2f((unsigned short)a0[i]);
        v[8 + i] = b2f((unsigned short)a1[i]);
    }
    float s = 0.0f, s2 = 0.0f;
    #pragma unroll
    for (int i = 0; i < 16; ++i) { s += v[i]; s2 += v[i] * v[i]; }
    #pragma unroll
    for (int m = 1; m < 64; m <<= 1) {
        s  += __shfl_xor(s, m);
        s2 += __shfl_xor(s2, m);
    }
    float mean = s * (1.0f / FC1);
    float var = s2 * (1.0f / FC1) - mean * mean;
    float inv = rsqrtf(var + 1e-5f);
    const float4* g4 = (const float4*)(g1 + lane * 16);
    const float4* b4 = (const float4*)(be1 + lane * 16);
    float gg[16], bb[16];
    #pragma unroll
    for (int q = 0; q < 4; ++q) {
        float4 gv = g4[q], bv = b4[q];
        gg[q * 4 + 0] = gv.x; gg[q * 4 + 1] = gv.y; gg[q * 4 + 2] = gv.z; gg[q * 4 + 3] = gv.w;
        bb[q * 4 + 0] = bv.x; bb[q * 4 + 1] = bv.y; bb[q * 4 + 2] = bv.z; bb[q * 4 + 3] = bv.w;
    }
    bf16x8 o0, o1;
    #pragma unroll
    for (int i = 0; i < 8; ++i) {
        float w = (v[i] - mean) * inv * gg[i] + bb[i];
        if (w < 0.0f) w = 0.0f;
        o0[i] = (short)f2b(w);
    }
    #pragma unroll
    for (int i = 0; i < 8; ++i) {
        float w = (v[8 + i] - mean) * inv * gg[8 + i] + bb[8 + i];
        if (w < 0.0f) w = 0.0f;
        o1[i] = (short)f2b(w);
    }
    unsigned short* q = zbn + (size_t)row * FC1 + lane * 16;
    *(bf16x8*)q = o0;
    *(bf16x8*)(q + 8) = o1;
}

// ---- FC2: 128x128 GEMM, K=1024 ----
__device__ __forceinline__ void fc2_body(int bid, int tid,
    const unsigned short* __restrict__ A, const unsigned short* __restrict__ Bt,
    const float* __restrict__ bias, unsigned short* __restrict__ outb,
    unsigned short (*As)[64], unsigned short (*Bs)[64]) {
    int tn = (bid >> 3) & 3;
    int tm = (bid & 7) + 8 * (bid >> 5);   // same-tm blocks share an XCD
    int lane = tid & 63, wave = tid >> 6;
    int wm = wave >> 1, wn = wave & 1;
    int r16 = lane & 15, quad = lane >> 4;
    int lr = (tid >> 3) & 7;
    int swz = ((tid & 7) ^ lr) * 8;
    const int K = FC1, N = FC2;

    floatx4 acc[4][4];
    #pragma unroll
    for (int i = 0; i < 4; ++i)
        #pragma unroll
        for (int j = 0; j < 4; ++j)
            acc[i][j] = (floatx4){0.0f, 0.0f, 0.0f, 0.0f};

    for (int k0 = 0; k0 < K; k0 += BK) {
        if (k0) __syncthreads();
        #pragma unroll
        for (int q = 0; q < 4; ++q) {
            gl_lds(A + (size_t)(tm * BM + (wave * 4 + q) * 8 + lr) * K + k0 + swz,
                   &As[(wave * 4 + q) * 8][0]);
            gl_lds(Bt + (size_t)(tn * BN + (wave * 4 + q) * 8 + lr) * K + k0 + swz,
                   &Bs[(wave * 4 + q) * 8][0]);
        }
        __syncthreads();
        #pragma unroll
        for (int h = 0; h < 2; ++h) {
            int col = (h * 32 + quad * 8) ^ ((r16 & 7) << 3);
            bf16x8 af[4], bfr[4];
            #pragma unroll
            for (int i = 0; i < 4; ++i)
                af[i] = *(const bf16x8*)&As[wm * 64 + i * 16 + r16][col];
            #pragma unroll
            for (int j = 0; j < 4; ++j)
                bfr[j] = *(const bf16x8*)&Bs[wn * 64 + j * 16 + r16][col];
            #pragma unroll
            for (int i = 0; i < 4; ++i)
                #pragma unroll
                for (int j = 0; j < 4; ++j)
                    acc[i][j] = __builtin_amdgcn_mfma_f32_16x16x32_bf16(af[i], bfr[j], acc[i][j], 0, 0, 0);
        }
    }
    __syncthreads();

    float bvj[4];
    #pragma unroll
    for (int j = 0; j < 4; ++j) bvj[j] = bias[tn * BN + wn * 64 + j * 16 + r16];

    #pragma unroll
    for (int i = 0; i < 4; ++i) {
        #pragma unroll
        for (int r = 0; r < 4; ++r) {
            int orow = tm * BM + wm * 64 + i * 16 + quad * 4 + r;
            #pragma unroll
            for (int j = 0; j < 4; ++j) {
                int ocol = tn * BN + wn * 64 + j * 16 + r16;
                outb[(size_t)orow * N + ocol] = f2b(acc[i][j][r] + bvj[j]);
            }
        }
    }
}

// ---- LN2 + ReLU + head for 16 rows ----
__device__ __forceinline__ void ln2head_body(int tm, int tid,
    const unsigned short* __restrict__ z, const float* __restrict__ g2,
    const float* __restrict__ be2, const unsigned short* __restrict__ wmu_t,
    const float* __restrict__ bmu, float* __restrict__ out,
    unsigned short (*Hs)[520], float (*hred)[64][4]) {
    {
        int row = tid >> 4;
        int sub = tid & 15;
        const unsigned short* src = z + (size_t)(tm * 16 + row) * FC2 + sub * 32;
        bf16x8 a0 = *(const bf16x8*)(src);
        bf16x8 a1 = *(const bf16x8*)(src + 8);
        bf16x8 a2 = *(const bf16x8*)(src + 16);
        bf16x8 a3 = *(const bf16x8*)(src + 24);
        float v[32];
        #pragma unroll
        for (int i = 0; i < 8; ++i) {
            v[i]      = b2f((unsigned short)a0[i]);
            v[8 + i]  = b2f((unsigned short)a1[i]);
            v[16 + i] = b2f((unsigned short)a2[i]);
            v[24 + i] = b2f((unsigned short)a3[i]);
        }
        float s = 0.0f, s2 = 0.0f;
        #pragma unroll
        for (int i = 0; i < 32; ++i) { s += v[i]; s2 += v[i] * v[i]; }
        #pragma unroll
        for (int m = 1; m < 16; m <<= 1) {
            s  += __shfl_xor(s, m);
            s2 += __shfl_xor(s2, m);
        }
        float mean = s * (1.0f / FC2);
        float var = s2 * (1.0f / FC2) - mean * mean;
        float inv = rsqrtf(var + 1e-5f);
        #pragma unroll
        for (int i = 0; i < 32; ++i) {
            int c = sub * 32 + i;
            float w = (v[i] - mean) * inv * g2[c] + be2[c];
            if (w < 0.0f) w = 0.0f;
            Hs[row][c] = f2b(w);
        }
    }
    __syncthreads();
    int lane = tid & 63, wave = tid >> 6;
    int r16 = lane & 15, quad = lane >> 4;
    floatx4 acc = {0.0f, 0.0f, 0.0f, 0.0f};
    #pragma unroll
    for (int st = 0; st < 4; ++st) {
        bf16x8 a = *(const bf16x8*)&Hs[r16][wave * 128 + st * 32 + quad * 8];
        bf16x8 b = *(const bf16x8*)(wmu_t + (size_t)r16 * FC2 + wave * 128 + st * 32 + quad * 8);
        acc = __builtin_amdgcn_mfma_f32_16x16x32_bf16(a, b, acc, 0, 0, 0);
    }
    #pragma unroll
    for (int r = 0; r < 4; ++r) hred[wave][lane][r] = acc[r];
    __syncthreads();
    if (wave == 0) {
        #pragma unroll
        for (int r = 0; r < 4; ++r) {
            float v = hred[0][lane][r] + hred[1][lane][r] + hred[2][lane][r] + hred[3][lane][r];
            v += bmu[r16];
            v = 1.0f / (1.0f + expf(-v));
            out[(size_t)(tm * 16 + quad * 4 + r) * N_ACT + r16] = v;
        }
    }
}

// ======================= cooperative kernels =======================

// ---- A: zero -> (scat | wtr | claim) -> bucket -> accumx ----
__global__ __launch_bounds__(256, 4) void graphc_k(
    const int* __restrict__ src, const int* __restrict__ dst,
    const int* __restrict__ agent_idx, int* __restrict__ nid,
    int* __restrict__ bcnt, unsigned long long* __restrict__ pairbuf,
    const float* __restrict__ Wgcn, const float* __restrict__ W1,
    const float* __restrict__ W2, const float* __restrict__ Wmu,
    unsigned short* __restrict__ wgcn_t, unsigned short* __restrict__ w1_t,
    unsigned short* __restrict__ w2_t, unsigned short* __restrict__ wmu_t,
    int* __restrict__ deg, int* __restrict__ ebuf,
    const float* __restrict__ x, unsigned short* __restrict__ agg) {
    __shared__ unsigned short Ts[64][72];
    __shared__ int hist[N_BUCKETS], base_[N_BUCKETS], cur[N_BUCKETS];
    __shared__ int nidl[256], lhist[256], lfill[256];
    cg::grid_group grid = cg::this_grid();
    int tid = threadIdx.x, blk = blockIdx.x;

    // phase 0: zero nid | bcnt (replaces hipMemsetAsync)
    {
        int idx = blk * 256 + tid;
        if (idx < N_NODES) nid[idx] = 0;
        if (idx < N_BUCKETS) bcnt[idx] = 0;
    }
    grid.sync();

    // phase 1: edge scatter | weight transpose | agent claim
    if (blk < SCAT_BLOCKS) {
        scat_body(blk, tid, src, dst, bcnt, pairbuf, hist, base_, cur);
    } else if (blk < SCAT_BLOCKS + WTR_BLOCKS) {
        wtr_block(blk - SCAT_BLOCKS, tid, Wgcn, W1, W2, Wmu,
                  wgcn_t, w1_t, w2_t, wmu_t, Ts);
    } else if (blk < SCAT_BLOCKS + WTR_BLOCKS + CLAIM_BLOCKS) {
        int i = (blk - SCAT_BLOCKS - WTR_BLOCKS) * 256 + tid;
        atomicCAS(&nid[agent_idx[i]], 0, i + 1);
    }
    grid.sync();

    // phase 2: per-bucket deg + ebuf fill
    if (blk < N_BUCKETS)
        bucket_body(blk, tid, bcnt, pairbuf, nid, deg, ebuf, nidl, lhist, lfill);
    grid.sync();

    // phase 3: aggregate (8 rows per block, 2 per wave)
    {
        int wave = tid >> 6, lane = tid & 63;
        #pragma unroll
        for (int it = 0; it < 2; ++it)
            accumx_row(blk * 8 + it * 4 + wave, lane, agent_idx, nid, deg, ebuf, x, agg);
    }
}

// ---- B: gcn -> fc1 -> ln1 -> fc2 -> ln2head ----
__global__ __launch_bounds__(256, 2) void mlpc_k(
    const unsigned short* __restrict__ agg, const unsigned short* __restrict__ wgcn_t,
    const float* __restrict__ bgcn, unsigned short* __restrict__ h_node,
    const int* __restrict__ agent, const int* __restrict__ nid,
    const unsigned short* __restrict__ w1_t, const float* __restrict__ b1,
    unsigned short* __restrict__ zb,
    const float* __restrict__ g1, const float* __restrict__ be1,
    unsigned short* __restrict__ zbn,
    const unsigned short* __restrict__ w2_t, const float* __restrict__ b2,
    unsigned short* __restrict__ zb2,
    const float* __restrict__ g2, const float* __restrict__ be2,
    const unsigned short* __restrict__ wmu_t, const float* __restrict__ bmu,
    float* __restrict__ out) {
    __shared__ __align__(16) char smem[32768];
    unsigned short (*As)[64] = (unsigned short (*)[64])smem;
    unsigned short (*Bs)[64] = (unsigned short (*)[64])(smem + 16384);
    cg::grid_group grid = cg::this_grid();
    int tid = threadIdx.x, bid = blockIdx.x;

    if (bid < 256) gcn_body(bid, tid, agg, wgcn_t, bgcn, h_node, As, Bs);
    grid.sync();

    fc1_body(bid, tid, h_node, agent, nid, w1_t, b1, zb, As, Bs);
    grid.sync();

    {
        int wave = tid >> 6, lane = tid & 63;
        #pragma unroll
        for (int it = 0; it < 4; ++it)
            ln1_row(bid * 16 + it * 4 + wave, lane, zb, g1, be1, zbn);
    }
    grid.sync();

    if (bid < 256) fc2_body(bid, tid, zbn, w2_t, b2, zb2, As, Bs);
    grid.sync();

    ln2head_body(bid, tid, zb2, g2, be2, wmu_t, bmu, out,
                 (unsigned short (*)[520])smem, (float (*)[64][4])(smem + 16640));
}

// ======================= sequential fallback kernels =======================

__global__ __launch_bounds__(256) void scat_k(const int* __restrict__ src,
    const int* __restrict__ dst, const int* __restrict__ agent_idx,
    int* __restrict__ nid, int* __restrict__ bcnt,
    unsigned long long* __restrict__ pairbuf,
    const float* __restrict__ Wgcn, const float* __restrict__ W1,
    const float* __restrict__ W2, const float* __restrict__ Wmu,
    unsigned short* __restrict__ wgcn_t, unsigned short* __restrict__ w1_t,
    unsigned short* __restrict__ w2_t, unsigned short* __restrict__ wmu_t) {
    __shared__ unsigned short Ts[64][72];
    __shared__ int hist[N_BUCKETS], base_[N_BUCKETS], cur[N_BUCKETS];
    int tid = threadIdx.x, blk = blockIdx.x;
    if (blk < SCAT_BLOCKS) {
        scat_body(blk, tid, src, dst, bcnt, pairbuf, hist, base_, cur);
    } else if (blk < SCAT_BLOCKS + WTR_BLOCKS) {
        wtr_block(blk - SCAT_BLOCKS, tid, Wgcn, W1, W2, Wmu,
                  wgcn_t, w1_t, w2_t, wmu_t, Ts);
    } else {
        int i = (blk - SCAT_BLOCKS - WTR_BLOCKS) * 256 + tid;
        atomicCAS(&nid[agent_idx[i]], 0, i + 1);
    }
}

__global__ __launch_bounds__(256) void bucket_k(const int* __restrict__ bcnt,
    const unsigned long long* __restrict__ pairbuf, const int* __restrict__ nid,
    int* __restrict__ deg, int* __restrict__ ebuf) {
    __shared__ int nidl[256], lhist[256], lfill[256];
    bucket_body(blockIdx.x, threadIdx.x, bcnt, pairbuf, nid, deg, ebuf, nidl, lhist, lfill);
}

__global__ __launch_bounds__(256) void accumx_k(const int* __restrict__ agent_idx,
    const int* __restrict__ nid, const int* __restrict__ deg,
    const int* __restrict__ ebuf, const float* __restrict__ x,
    unsigned short* __restrict__ agg) {
    accumx_row(blockIdx.x * 4 + (threadIdx.x >> 6), threadIdx.x & 63,
               agent_idx, nid, deg, ebuf, x, agg);
}

__global__ __launch_bounds__(256) void gemm_gcn_k(const unsigned short* __restrict__ A,
    const unsigned short* __restrict__ Bt, const float* __restrict__ bias,
    unsigned short* __restrict__ outb) {
    __shared__ unsigned short As[64][64];
    __shared__ unsigned short Bs[128][64];
    gcn_body(blockIdx.x, threadIdx.x, A, Bt, bias, outb, As, Bs);
}

__global__ __launch_bounds__(256) void gemm_fc1_k(const unsigned short* __restrict__ h_node,
    const int* __restrict__ agent, const int* __restrict__ nid,
    const unsigned short* __restrict__ Bt, const float* __restrict__ bias,
    unsigned short* __restrict__ outb) {
    __shared__ unsigned short As[BM][64];
    __shared__ unsigned short Bs[BN][64];
    fc1_body(blockIdx.x, threadIdx.x, h_node, agent, nid, Bt, bias, outb, As, Bs);
}

__global__ __launch_bounds__(256) void ln1_k(const unsigned short* __restrict__ zb,
    const float* __restrict__ g1, const float* __restrict__ be1,
    unsigned short* __restrict__ zbn) {
    int wave = threadIdx.x >> 6, lane = threadIdx.x & 63;
    #pragma unroll
    for (int it = 0; it < 4; ++it)
        ln1_row(blockIdx.x * 16 + it * 4 + wave, lane, zb, g1, be1, zbn);
}

__global__ __launch_bounds__(256) void gemm_fc2_k(const unsigned short* __restrict__ A,
    const unsigned short* __restrict__ Bt, const float* __restrict__ bias,
    unsigned short* __restrict__ outb) {
    __shared__ unsigned short As[BM][64];
    __shared__ unsigned short Bs[BN][64];
    fc2_body(blockIdx.x, threadIdx.x, A, Bt, bias, outb, As, Bs);
}

__global__ __launch_bounds__(256) void ln2head_k(const unsigned short* __restrict__ z,
    const float* __restrict__ g2, const float* __restrict__ be2,
    const unsigned short* __restrict__ wmu_t, const float* __restrict__ bmu,
    float* __restrict__ out) {
    __shared__ unsigned short Hs[16][520];
    __shared__ float hred[4][64][4];
    ln2head_body(blockIdx.x, threadIdx.x, z, g2, be2, wmu_t, bmu, out, Hs, hred);
}

extern "C" void kernel_launch(void* const* d_in, const int* in_sizes, int n_in,
                              void* d_out, int out_size, void* d_ws, size_t ws_size,
                              hipStream_t stream) {
    const float* x    = (const float*)d_in[0];
    const int*   ei   = (const int*)d_in[1];
    const int*   agent= (const int*)d_in[2];
    const float* Wgcn = (const float*)d_in[3];
    const float* bgcn = (const float*)d_in[4];
    const float* W1   = (const float*)d_in[5];
    const float* b1   = (const float*)d_in[6];
    const float* g1   = (const float*)d_in[7];
    const float* be1  = (const float*)d_in[8];
    const float* W2   = (const float*)d_in[9];
    const float* b2   = (const float*)d_in[10];
    const float* g2   = (const float*)d_in[11];
    const float* be2  = (const float*)d_in[12];
    const float* Wmu  = (const float*)d_in[13];
    const float* bmu  = (const float*)d_in[14];
    float* out = (float*)d_out;

    const int* srcp = ei;
    const int* dstp = ei + N_EDGES;

    // workspace layout (256B aligned)
    char* ws = (char*)d_ws;
    size_t off = 0;
    char* zero_base = ws;
    int* nid  = (int*)(ws + off);      off += ((size_t)N_NODES * 4 + 255) & ~(size_t)255;
    int* bcnt = (int*)(ws + off);      off += ((size_t)N_BUCKETS * 4 + 255) & ~(size_t)255;
    size_t zero_bytes = off;
    int* deg  = (int*)(ws + off);      off += ((size_t)N_NODES * 4 + 255) & ~(size_t)255;
    unsigned long long* pairbuf = (unsigned long long*)(ws + off);
    off += ((size_t)N_BUCKETS * BUCKET_CAP * 8 + 255) & ~(size_t)255;
    int* ebuf = (int*)(ws + off);      off += ((size_t)N_AGENTS * EB_STRIDE * 4 + 255) & ~(size_t)255;
    unsigned short* wgcn_t = (unsigned short*)(ws + off); off += ((size_t)IN_DIM * HID * 2 + 255) & ~(size_t)255;
    unsigned short* w1_t   = (unsigned short*)(ws + off); off += ((size_t)HID * FC1 * 2 + 255) & ~(size_t)255;
    unsigned short* w2_t   = (unsigned short*)(ws + off); off += ((size_t)FC1 * FC2 * 2 + 255) & ~(size_t)255;
    unsigned short* wmu_t  = (unsigned short*)(ws + off); off += ((size_t)FC2 * N_ACT * 2 + 255) & ~(size_t)255;
    unsigned short* agg    = (unsigned short*)(ws + off); off += ((size_t)N_AGENTS * IN_DIM * 2 + 255) & ~(size_t)255;
    unsigned short* h_node = (unsigned short*)(ws + off); off += ((size_t)N_AGENTS * HID * 2 + 255) & ~(size_t)255;
    unsigned short* zb  = (unsigned short*)(ws + off);    off += ((size_t)N_AGENTS * FC1 * 2 + 255) & ~(size_t)255;
    unsigned short* zbn = (unsigned short*)(ws + off);    off += ((size_t)N_AGENTS * FC1 * 2 + 255) & ~(size_t)255;
    unsigned short* zb2 = (unsigned short*)(ws + off);    off += ((size_t)N_AGENTS * FC2 * 2 + 255) & ~(size_t)255;

    // ---- kernel A (cooperative): zero -> scat|wtr|claim -> bucket -> accumx ----
    void* argsA[] = { (void*)&srcp, (void*)&dstp, (void*)&agent, (void*)&nid,
                      (void*)&bcnt, (void*)&pairbuf, (void*)&Wgcn, (void*)&W1,
                      (void*)&W2, (void*)&Wmu, (void*)&wgcn_t, (void*)&w1_t,
                      (void*)&w2_t, (void*)&wmu_t, (void*)&deg, (void*)&ebuf,
                      (void*)&x, (void*)&agg };
    hipError_t eA = hipLaunchCooperativeKernel((const void*)graphc_k, dim3(GRID_A),
                                               dim3(256), argsA, 0, stream);
    if (eA != hipSuccess) {
        hipMemsetAsync(zero_base, 0, zero_bytes, stream);
        scat_k<<<SCAT_BLOCKS + WTR_BLOCKS + CLAIM_BLOCKS, 256, 0, stream>>>(
            srcp, dstp, agent, nid, bcnt, pairbuf,
            Wgcn, W1, W2, Wmu, wgcn_t, w1_t, w2_t, wmu_t);
        bucket_k<<<N_BUCKETS, 256, 0, stream>>>(bcnt, pairbuf, nid, deg, ebuf);
        accumx_k<<<N_AGENTS / 4, 256, 0, stream>>>(agent, nid, deg, ebuf, x, agg);
    }

    // ---- kernel B (cooperative): gcn -> fc1 -> ln1 -> fc2 -> ln2head ----
    void* argsB[] = { (void*)&agg, (void*)&wgcn_t, (void*)&bgcn, (void*)&h_node,
                      (void*)&agent, (void*)&nid, (void*)&w1_t, (void*)&b1,
                      (void*)&zb, (void*)&g1, (void*)&be1, (void*)&zbn,
                      (void*)&w2_t, (void*)&b2, (void*)&zb2, (void*)&g2,
                      (void*)&be2, (void*)&wmu_t, (void*)&bmu, (void*)&out };
    hipError_t eB = hipLaunchCooperativeKernel((const void*)mlpc_k, dim3(GRID_B),
                                               dim3(256), argsB, 0, stream);
    if (eB != hipSuccess) {
        gemm_gcn_k<<<(HID / 128) * (N_AGENTS / 64), 256, 0, stream>>>(agg, wgcn_t, bgcn, h_node);
        gemm_fc1_k<<<(FC1 / BN) * (N_AGENTS / BM), 256, 0, stream>>>(h_node, agent, nid, w1_t, b1, zb);
        ln1_k<<<N_AGENTS / 16, 256, 0, stream>>>(zb, g1, be1, zbn);
        gemm_fc2_k<<<(FC2 / 128) * (N_AGENTS / 128), 256, 0, stream>>>(zbn, w2_t, b2, zb2);
        ln2head_k<<<N_AGENTS / 16, 256, 0, stream>>>(zb2, g2, be2, wmu_t, bmu, out);
    }
}

// Round 6
// 180.477 us; speedup vs baseline: 4.0861x; 4.0861x over previous
//
#include <hip/hip_runtime.h>
#include <hip/hip_bf16.h>
#include <math.h>

#define N_NODES  50000
#define N_EDGES  800000
#define IN_DIM   128
#define HID      256
#define FC1      1024
#define FC2      512
#define N_ACT    16
#define N_AGENTS 8192

#define BK       64
#define BM       128
#define BN       128

#define EB_STRIDE    64        // max deg per claimed node (Binomial(800k,1/50k)~Poisson-16)

#define SCAT_CHUNK   2048
#define SCAT_BLOCKS  ((N_EDGES + SCAT_CHUNK - 1) / SCAT_CHUNK)   // 391
#define N_BUCKETS    196       // ceil(50000/256): 256-node ranges
#define BUCKET_CAP   4608      // mean 4082, std ~64 -> 8 sigma headroom
#define WTR_BLOCKS   208
#define CLAIM_BLOCKS (N_AGENTS / 256)   // 32

typedef short bf16x8 __attribute__((ext_vector_type(8)));
typedef float floatx4 __attribute__((ext_vector_type(4)));

__device__ __forceinline__ unsigned short f2b(float f) {
    union { float f; unsigned int i; } v;
    v.f = f;
    unsigned int lsb = (v.i >> 16) & 1u;
    v.i += 0x7fffu + lsb;            // round-to-nearest-even
    return (unsigned short)(v.i >> 16);
}

__device__ __forceinline__ float b2f(unsigned short u) {
    union { unsigned int i; float f; } v;
    v.i = ((unsigned int)u) << 16;
    return v.f;
}

// async global->LDS, 16B per lane. LDS dest = wave-uniform base + lane*16 (linear).
__device__ __forceinline__ void gl_lds(const unsigned short* g, unsigned short* l) {
    __builtin_amdgcn_global_load_lds(
        (const __attribute__((address_space(1))) void*)g,
        (__attribute__((address_space(3))) void*)l, 16, 0, 0);
}

// ---- weight transpose tile helper (f32 [K,N] -> bf16 [N,K], 64x64 via LDS) ----
__device__ __forceinline__ void wtr_block(int b, int tid,
    const float* __restrict__ Wgcn, const float* __restrict__ W1,
    const float* __restrict__ W2, const float* __restrict__ Wmu,
    unsigned short* __restrict__ wgcn_t, unsigned short* __restrict__ w1_t,
    unsigned short* __restrict__ w2_t, unsigned short* __restrict__ wmu_t,
    unsigned short (*Ts)[72]) {
    const float* src; unsigned short* dstw; int K, N, tk, tn;
    if (b < 8)        { src = Wgcn; dstw = wgcn_t; K = IN_DIM; N = HID;  tk = b >> 2;        tn = b & 3; }
    else if (b < 72)  { int bb = b - 8;  src = W1; dstw = w1_t; K = HID;  N = FC1;  tk = bb >> 4; tn = bb & 15; }
    else if (b < 200) { int bb = b - 72; src = W2; dstw = w2_t; K = FC1;  N = FC2;  tk = bb >> 3; tn = bb & 7; }
    else              { int bb = b - 200; src = Wmu; dstw = wmu_t; K = FC2; N = N_ACT; tk = bb;   tn = 0; }
    int k0 = tk * 64, n0 = tn * 64;
    int r = tid >> 2;
    int cc = (tid & 3) * 16;
    if (n0 + cc < N) {
        const float* p = src + (size_t)(k0 + r) * N + n0 + cc;
        #pragma unroll
        for (int i = 0; i < 16; i += 4) {
            float4 v = *(const float4*)(p + i);
            Ts[r][cc + i + 0] = f2b(v.x);
            Ts[r][cc + i + 1] = f2b(v.y);
            Ts[r][cc + i + 2] = f2b(v.z);
            Ts[r][cc + i + 3] = f2b(v.w);
        }
    }
    __syncthreads();
    int n = tid >> 2;
    if (n0 + n < N) {
        bf16x8 o0, o1;
        #pragma unroll
        for (int i = 0; i < 8; ++i) o0[i] = (short)Ts[cc + i][n];
        #pragma unroll
        for (int i = 0; i < 8; ++i) o1[i] = (short)Ts[cc + 8 + i][n];
        unsigned short* q = dstw + (size_t)(n0 + n) * K + k0 + cc;
        *(bf16x8*)q = o0;
        *(bf16x8*)(q + 8) = o1;
    }
}

// ---- scatter edges into 256-node-range buckets; tail blocks: wtr + claim ----
__global__ __launch_bounds__(256) void scat_k(const int* __restrict__ src,
                                              const int* __restrict__ dst,
                                              const int* __restrict__ agent_idx,
                                              int* __restrict__ nid,
                                              int* __restrict__ bcnt,
                                              unsigned long long* __restrict__ pairbuf,
                                              const float* __restrict__ Wgcn,
                                              const float* __restrict__ W1,
                                              const float* __restrict__ W2,
                                              const float* __restrict__ Wmu,
                                              unsigned short* __restrict__ wgcn_t,
                                              unsigned short* __restrict__ w1_t,
                                              unsigned short* __restrict__ w2_t,
                                              unsigned short* __restrict__ wmu_t) {
    __shared__ unsigned short Ts[64][72];
    __shared__ int hist[N_BUCKETS], base_[N_BUCKETS], cur[N_BUCKETS];
    int tid = threadIdx.x;
    int blk = blockIdx.x;
    if (blk >= SCAT_BLOCKS) {
        int bb = blk - SCAT_BLOCKS;
        if (bb < WTR_BLOCKS) {
            wtr_block(bb, tid, Wgcn, W1, W2, Wmu, wgcn_t, w1_t, w2_t, wmu_t, Ts);
        } else {
            int i = (bb - WTR_BLOCKS) * 256 + tid;   // exactly N_AGENTS threads
            atomicCAS(&nid[agent_idx[i]], 0, i + 1);
        }
        return;
    }
    if (tid < N_BUCKETS) { hist[tid] = 0; cur[tid] = 0; }
    __syncthreads();
    int e0 = blk * SCAT_CHUNK;
    int dv[8];
    #pragma unroll
    for (int i = 0; i < 8; ++i) {
        int e = e0 + i * 256 + tid;
        dv[i] = (e < N_EDGES) ? dst[e] : -1;
        if (dv[i] >= 0) atomicAdd(&hist[dv[i] >> 8], 1);
    }
    __syncthreads();
    if (tid < N_BUCKETS && hist[tid] > 0)
        base_[tid] = atomicAdd(&bcnt[tid], hist[tid]);   // one global atomic per bucket per block
    __syncthreads();
    #pragma unroll
    for (int i = 0; i < 8; ++i) {
        int e = e0 + i * 256 + tid;
        if (e < N_EDGES) {
            int d = dv[i];
            int bk = d >> 8;
            int p = base_[bk] + atomicAdd(&cur[bk], 1);
            if (p < BUCKET_CAP)
                pairbuf[(size_t)bk * BUCKET_CAP + p] =
                    ((unsigned long long)(unsigned)src[e] << 32) | (unsigned)d;
        }
    }
}

// ---- per-bucket: exact deg (LDS hist, no global atomics) + claimed ebuf fill ----
__global__ __launch_bounds__(256) void bucket_k(const int* __restrict__ bcnt,
                                                const unsigned long long* __restrict__ pairbuf,
                                                const int* __restrict__ nid,
                                                int* __restrict__ deg,
                                                int* __restrict__ ebuf) {
    __shared__ int nidl[256], lhist[256], lfill[256];
    int b = blockIdx.x, tid = threadIdx.x;
    int node = b * 256 + tid;
    nidl[tid] = (node < N_NODES) ? nid[node] : 0;
    lhist[tid] = 0;
    lfill[tid] = 0;
    __syncthreads();
    int n = bcnt[b];
    if (n > BUCKET_CAP) n = BUCKET_CAP;
    const unsigned long long* pb = pairbuf + (size_t)b * BUCKET_CAP;
    for (int i = tid; i < n; i += 256) {
        unsigned long long pr = pb[i];
        int d = (int)(unsigned)pr;          // low 32 = dst
        int s = (int)(pr >> 32);            // high 32 = src
        int l = d & 255;
        atomicAdd(&lhist[l], 1);
        int cc = nidl[l];
        if (cc != 0) {
            int p = atomicAdd(&lfill[l], 1);
            if (p < EB_STRIDE) ebuf[((cc - 1) << 6) + p] = s;
        }
    }
    __syncthreads();
    if (node < N_NODES) deg[node] = lhist[tid];   // full overwrite -> no memset needed
}

// ---- aggregate raw x per winning agent slot: one wave per row ----
// all gather addresses known up-front (ej preloaded); 4x unroll issues 4
// independent row-loads per iter to hide L2/HBM latency. add order preserved.
__global__ __launch_bounds__(256) void accumx_k(const int* __restrict__ agent_idx,
                                                const int* __restrict__ nid,
                                                const int* __restrict__ deg,
                                                const int* __restrict__ ebuf,
                                                const float* __restrict__ x,
                                                unsigned short* __restrict__ agg) {
    int c = blockIdx.x * 4 + (threadIdx.x >> 6);
    int lane = threadIdx.x & 63;
    int n = agent_idx[c];
    float ax = 0.0f, ay = 0.0f;
    if (nid[n] == c + 1) {
        int dn_i = deg[n];
        int cnt = dn_i < EB_STRIDE ? dn_i : EB_STRIDE;
        float dn = rsqrtf((float)(dn_i + 1));
        const int* eb = ebuf + (c << 6);
        int ej = (lane < cnt) ? eb[lane] : n;          // coalesced neighbor list
        float wl = rsqrtf((float)(deg[ej] + 1)) * dn;  // per-lane weight, gather once
        const float* xl = x + lane * 2;
        int i = 0;
        for (; i + 4 <= cnt; i += 4) {
            int s0 = __shfl(ej, i),     s1 = __shfl(ej, i + 1);
            int s2 = __shfl(ej, i + 2), s3 = __shfl(ej, i + 3);
            float w0 = __shfl(wl, i),     w1 = __shfl(wl, i + 1);
            float w2 = __shfl(wl, i + 2), w3 = __shfl(wl, i + 3);
            float2 u0 = *(const float2*)(xl + (size_t)s0 * IN_DIM);
            float2 u1 = *(const float2*)(xl + (size_t)s1 * IN_DIM);
            float2 u2 = *(const float2*)(xl + (size_t)s2 * IN_DIM);
            float2 u3 = *(const float2*)(xl + (size_t)s3 * IN_DIM);
            ax += w0 * u0.x; ay += w0 * u0.y;
            ax += w1 * u1.x; ay += w1 * u1.y;
            ax += w2 * u2.x; ay += w2 * u2.y;
            ax += w3 * u3.x; ay += w3 * u3.y;
        }
        for (; i < cnt; ++i) {
            int s = __shfl(ej, i);
            float w = __shfl(wl, i);
            float2 u = *(const float2*)(xl + (size_t)s * IN_DIM);
            ax += w * u.x;
            ay += w * u.y;
        }
        float2 u = *(const float2*)(xl + (size_t)n * IN_DIM);
        float w2s = dn * dn;
        ax += w2s * u.x;
        ay += w2s * u.y;
    }
    unsigned int pk = (unsigned int)f2b(ax) | ((unsigned int)f2b(ay) << 16);
    *(unsigned int*)(agg + (size_t)c * IN_DIM + lane * 2) = pk;
}

// ==== GEMMs: m97-style global_load_lds staging, linear LDS + XOR swizzle ====
// write side: lane L stages global 16B-chunk ((L&7)^(L>>3)) of row (ci*8+L>>3)
//   -> LDS[row][chunk] holds global chunk (chunk ^ (row&7))
// read side: fragment col (ushorts) = (h*32 + quad*8) ^ ((r16&7)<<3)
//   -> 8 distinct 16B chunks across r16 lanes = conflict-free

// ---- GCN GEMM: 64x128 tile, BK=64, bf16(relu(v+bias)) out ----
__global__ __launch_bounds__(256) void gemm_gcn_k(const unsigned short* __restrict__ A,
                                                  const unsigned short* __restrict__ Bt,
                                                  const float* __restrict__ bias,
                                                  unsigned short* __restrict__ outb) {
    __shared__ unsigned short As[64][64];
    __shared__ unsigned short Bs[128][64];
    int bid = blockIdx.x;
    int tn = (bid >> 3) & 1;
    int tm = (bid & 7) + 8 * (bid >> 4);   // same-tm blocks share an XCD
    int tid = threadIdx.x;
    int lane = tid & 63, wave = tid >> 6;
    int r16 = lane & 15, quad = lane >> 4;
    int lr = (tid >> 3) & 7;
    int swz = ((tid & 7) ^ lr) * 8;
    const int K = IN_DIM, N = HID;

    floatx4 acc[4][2];
    #pragma unroll
    for (int i = 0; i < 4; ++i)
        #pragma unroll
        for (int j = 0; j < 2; ++j)
            acc[i][j] = (floatx4){0.0f, 0.0f, 0.0f, 0.0f};

    for (int k0 = 0; k0 < K; k0 += BK) {
        if (k0) __syncthreads();
        #pragma unroll
        for (int q = 0; q < 2; ++q)
            gl_lds(A + (size_t)(tm * 64 + (wave * 2 + q) * 8 + lr) * K + k0 + swz,
                   &As[(wave * 2 + q) * 8][0]);
        #pragma unroll
        for (int q = 0; q < 4; ++q)
            gl_lds(Bt + (size_t)(tn * 128 + (wave * 4 + q) * 8 + lr) * K + k0 + swz,
                   &Bs[(wave * 4 + q) * 8][0]);
        __syncthreads();
        #pragma unroll
        for (int h = 0; h < 2; ++h) {
            int col = (h * 32 + quad * 8) ^ ((r16 & 7) << 3);
            bf16x8 af[4], bfr[2];
            #pragma unroll
            for (int i = 0; i < 4; ++i)
                af[i] = *(const bf16x8*)&As[i * 16 + r16][col];
            #pragma unroll
            for (int j = 0; j < 2; ++j)
                bfr[j] = *(const bf16x8*)&Bs[wave * 32 + j * 16 + r16][col];
            #pragma unroll
            for (int i = 0; i < 4; ++i)
                #pragma unroll
                for (int j = 0; j < 2; ++j)
                    acc[i][j] = __builtin_amdgcn_mfma_f32_16x16x32_bf16(af[i], bfr[j], acc[i][j], 0, 0, 0);
        }
    }

    #pragma unroll
    for (int j = 0; j < 2; ++j) {
        int ocol = tn * 128 + wave * 32 + j * 16 + r16;
        float bv = bias[ocol];
        #pragma unroll
        for (int i = 0; i < 4; ++i) {
            int orow = tm * 64 + i * 16 + quad * 4;
            #pragma unroll
            for (int r = 0; r < 4; ++r) {
                float v = acc[i][j][r] + bv;
                if (v < 0.0f) v = 0.0f;
                outb[(size_t)(orow + r) * N + ocol] = f2b(v);
            }
        }
    }
}

// ---- FC1: 128x128 gather GEMM, gload_lds staging -> zb (raw, pre-LN) ----
__global__ __launch_bounds__(256) void gemm_fc1_k(const unsigned short* __restrict__ h_node,
                                                  const int* __restrict__ agent,
                                                  const int* __restrict__ nid,
                                                  const unsigned short* __restrict__ Bt,
                                                  const float* __restrict__ bias,
                                                  unsigned short* __restrict__ outb) {
    __shared__ unsigned short As[BM][64];
    __shared__ unsigned short Bs[BN][64];
    int bid = blockIdx.x;
    int tn = (bid >> 3) & 7;
    int tm = (bid & 7) + 8 * (bid >> 6);   // same-tm blocks share an XCD
    int tid = threadIdx.x;
    int lane = tid & 63, wave = tid >> 6;
    int wm = wave >> 1, wn = wave & 1;
    int r16 = lane & 15, quad = lane >> 4;
    int lr = (tid >> 3) & 7;
    int swz = ((tid & 7) ^ lr) * 8;
    const int K = HID, N = FC1;

    int cA[4];
    #pragma unroll
    for (int q = 0; q < 4; ++q)
        cA[q] = nid[agent[tm * BM + (wave * 4 + q) * 8 + lr]] - 1;

    floatx4 acc[4][4];
    #pragma unroll
    for (int i = 0; i < 4; ++i)
        #pragma unroll
        for (int j = 0; j < 4; ++j)
            acc[i][j] = (floatx4){0.0f, 0.0f, 0.0f, 0.0f};

    for (int k0 = 0; k0 < K; k0 += BK) {
        if (k0) __syncthreads();
        #pragma unroll
        for (int q = 0; q < 4; ++q) {
            gl_lds(h_node + (size_t)cA[q] * K + k0 + swz,
                   &As[(wave * 4 + q) * 8][0]);
            gl_lds(Bt + (size_t)(tn * BN + (wave * 4 + q) * 8 + lr) * K + k0 + swz,
                   &Bs[(wave * 4 + q) * 8][0]);
        }
        __syncthreads();
        #pragma unroll
        for (int h = 0; h < 2; ++h) {
            int col = (h * 32 + quad * 8) ^ ((r16 & 7) << 3);
            bf16x8 af[4], bfr[4];
            #pragma unroll
            for (int i = 0; i < 4; ++i)
                af[i] = *(const bf16x8*)&As[wm * 64 + i * 16 + r16][col];
            #pragma unroll
            for (int j = 0; j < 4; ++j)
                bfr[j] = *(const bf16x8*)&Bs[wn * 64 + j * 16 + r16][col];
            #pragma unroll
            for (int i = 0; i < 4; ++i)
                #pragma unroll
                for (int j = 0; j < 4; ++j)
                    acc[i][j] = __builtin_amdgcn_mfma_f32_16x16x32_bf16(af[i], bfr[j], acc[i][j], 0, 0, 0);
        }
    }

    float bvj[4];
    #pragma unroll
    for (int j = 0; j < 4; ++j) bvj[j] = bias[tn * BN + wn * 64 + j * 16 + r16];

    #pragma unroll
    for (int i = 0; i < 4; ++i) {
        #pragma unroll
        for (int r = 0; r < 4; ++r) {
            int orow = tm * BM + wm * 64 + i * 16 + quad * 4 + r;
            #pragma unroll
            for (int j = 0; j < 4; ++j) {
                int ocol = tn * BN + wn * 64 + j * 16 + r16;
                outb[(size_t)orow * N + ocol] = f2b(acc[i][j][r] + bvj[j]);
            }
        }
    }
}

// ---- LN1 apply (stats in-register, one wave per row) + affine + ReLU ----
__global__ __launch_bounds__(256) void ln1_k(const unsigned short* __restrict__ zb,
                                             const float* __restrict__ g1,
                                             const float* __restrict__ be1,
                                             unsigned short* __restrict__ zbn) {
    int row = blockIdx.x * 4 + (threadIdx.x >> 6);
    int lane = threadIdx.x & 63;
    const unsigned short* p = zb + (size_t)row * FC1 + lane * 16;
    bf16x8 a0 = *(const bf16x8*)p;
    bf16x8 a1 = *(const bf16x8*)(p + 8);
    float v[16];
    #pragma unroll
    for (int i = 0; i < 8; ++i) {
        v[i]     = b2f((unsigned short)a0[i]);
        v[8 + i] = b2f((unsigned short)a1[i]);
    }
    float s = 0.0f, s2 = 0.0f;
    #pragma unroll
    for (int i = 0; i < 16; ++i) { s += v[i]; s2 += v[i] * v[i]; }
    #pragma unroll
    for (int m = 1; m < 64; m <<= 1) {
        s  += __shfl_xor(s, m);
        s2 += __shfl_xor(s2, m);
    }
    float mean = s * (1.0f / FC1);
    float var = s2 * (1.0f / FC1) - mean * mean;
    float inv = rsqrtf(var + 1e-5f);
    const float4* g4 = (const float4*)(g1 + lane * 16);
    const float4* b4 = (const float4*)(be1 + lane * 16);
    float gg[16], bb[16];
    #pragma unroll
    for (int q = 0; q < 4; ++q) {
        float4 gv = g4[q], bv = b4[q];
        gg[q * 4 + 0] = gv.x; gg[q * 4 + 1] = gv.y; gg[q * 4 + 2] = gv.z; gg[q * 4 + 3] = gv.w;
        bb[q * 4 + 0] = bv.x; bb[q * 4 + 1] = bv.y; bb[q * 4 + 2] = bv.z; bb[q * 4 + 3] = bv.w;
    }
    bf16x8 o0, o1;
    #pragma unroll
    for (int i = 0; i < 8; ++i) {
        float w = (v[i] - mean) * inv * gg[i] + bb[i];
        if (w < 0.0f) w = 0.0f;
        o0[i] = (short)f2b(w);
    }
    #pragma unroll
    for (int i = 0; i < 8; ++i) {
        float w = (v[8 + i] - mean) * inv * gg[8 + i] + bb[8 + i];
        if (w < 0.0f) w = 0.0f;
        o1[i] = (short)f2b(w);
    }
    unsigned short* q = zbn + (size_t)row * FC1 + lane * 16;
    *(bf16x8*)q = o0;
    *(bf16x8*)(q + 8) = o1;
}

// ---- FC2: 128x128 GEMM, gload_lds staging (A already LN'd) ----
__global__ __launch_bounds__(256) void gemm_fc2_k(const unsigned short* __restrict__ A,
                                                  const unsigned short* __restrict__ Bt,
                                                  const float* __restrict__ bias,
                                                  unsigned short* __restrict__ outb) {
    __shared__ unsigned short As[BM][64];
    __shared__ unsigned short Bs[BN][64];
    int bid = blockIdx.x;
    int tn = (bid >> 3) & 3;
    int tm = (bid & 7) + 8 * (bid >> 5);   // same-tm blocks share an XCD
    int tid = threadIdx.x;
    int lane = tid & 63, wave = tid >> 6;
    int wm = wave >> 1, wn = wave & 1;
    int r16 = lane & 15, quad = lane >> 4;
    int lr = (tid >> 3) & 7;
    int swz = ((tid & 7) ^ lr) * 8;
    const int K = FC1, N = FC2;

    floatx4 acc[4][4];
    #pragma unroll
    for (int i = 0; i < 4; ++i)
        #pragma unroll
        for (int j = 0; j < 4; ++j)
            acc[i][j] = (floatx4){0.0f, 0.0f, 0.0f, 0.0f};

    for (int k0 = 0; k0 < K; k0 += BK) {
        if (k0) __syncthreads();
        #pragma unroll
        for (int q = 0; q < 4; ++q) {
            gl_lds(A + (size_t)(tm * BM + (wave * 4 + q) * 8 + lr) * K + k0 + swz,
                   &As[(wave * 4 + q) * 8][0]);
            gl_lds(Bt + (size_t)(tn * BN + (wave * 4 + q) * 8 + lr) * K + k0 + swz,
                   &Bs[(wave * 4 + q) * 8][0]);
        }
        __syncthreads();
        #pragma unroll
        for (int h = 0; h < 2; ++h) {
            int col = (h * 32 + quad * 8) ^ ((r16 & 7) << 3);
            bf16x8 af[4], bfr[4];
            #pragma unroll
            for (int i = 0; i < 4; ++i)
                af[i] = *(const bf16x8*)&As[wm * 64 + i * 16 + r16][col];
            #pragma unroll
            for (int j = 0; j < 4; ++j)
                bfr[j] = *(const bf16x8*)&Bs[wn * 64 + j * 16 + r16][col];
            #pragma unroll
            for (int i = 0; i < 4; ++i)
                #pragma unroll
                for (int j = 0; j < 4; ++j)
                    acc[i][j] = __builtin_amdgcn_mfma_f32_16x16x32_bf16(af[i], bfr[j], acc[i][j], 0, 0, 0);
        }
    }

    float bvj[4];
    #pragma unroll
    for (int j = 0; j < 4; ++j) bvj[j] = bias[tn * BN + wn * 64 + j * 16 + r16];

    #pragma unroll
    for (int i = 0; i < 4; ++i) {
        #pragma unroll
        for (int r = 0; r < 4; ++r) {
            int orow = tm * BM + wm * 64 + i * 16 + quad * 4 + r;
            #pragma unroll
            for (int j = 0; j < 4; ++j) {
                int ocol = tn * BN + wn * 64 + j * 16 + r16;
                outb[(size_t)orow * N + ocol] = f2b(acc[i][j][r] + bvj[j]);
            }
        }
    }
}

// ---- fused LN2 + ReLU + head, 16 rows/block (512 blocks) ----
__global__ __launch_bounds__(256) void ln2head_k(const unsigned short* __restrict__ z,
                                                 const float* __restrict__ g2,
                                                 const float* __restrict__ be2,
                                                 const unsigned short* __restrict__ wmu_t,
                                                 const float* __restrict__ bmu,
                                                 float* __restrict__ out) {
    __shared__ unsigned short Hs[16][520];
    __shared__ float hred[4][64][4];
    int tid = threadIdx.x;
    int tm = blockIdx.x;
    {
        int row = tid >> 4;
        int sub = tid & 15;
        const unsigned short* src = z + (size_t)(tm * 16 + row) * FC2 + sub * 32;
        bf16x8 a0 = *(const bf16x8*)(src);
        bf16x8 a1 = *(const bf16x8*)(src + 8);
        bf16x8 a2 = *(const bf16x8*)(src + 16);
        bf16x8 a3 = *(const bf16x8*)(src + 24);
        float v[32];
        #pragma unroll
        for (int i = 0; i < 8; ++i) {
            v[i]      = b2f((unsigned short)a0[i]);
            v[8 + i]  = b2f((unsigned short)a1[i]);
            v[16 + i] = b2f((unsigned short)a2[i]);
            v[24 + i] = b2f((unsigned short)a3[i]);
        }
        float s = 0.0f, s2 = 0.0f;
        #pragma unroll
        for (int i = 0; i < 32; ++i) { s += v[i]; s2 += v[i] * v[i]; }
        #pragma unroll
        for (int m = 1; m < 16; m <<= 1) {
            s  += __shfl_xor(s, m);
            s2 += __shfl_xor(s2, m);
        }
        float mean = s * (1.0f / FC2);
        float var = s2 * (1.0f / FC2) - mean * mean;
        float inv = rsqrtf(var + 1e-5f);
        #pragma unroll
        for (int i = 0; i < 32; ++i) {
            int c = sub * 32 + i;
            float w = (v[i] - mean) * inv * g2[c] + be2[c];
            if (w < 0.0f) w = 0.0f;
            Hs[row][c] = f2b(w);
        }
    }
    __syncthreads();
    int lane = tid & 63, wave = tid >> 6;
    int r16 = lane & 15, quad = lane >> 4;
    floatx4 acc = {0.0f, 0.0f, 0.0f, 0.0f};
    #pragma unroll
    for (int st = 0; st < 4; ++st) {
        bf16x8 a = *(const bf16x8*)&Hs[r16][wave * 128 + st * 32 + quad * 8];
        bf16x8 b = *(const bf16x8*)(wmu_t + (size_t)r16 * FC2 + wave * 128 + st * 32 + quad * 8);
        acc = __builtin_amdgcn_mfma_f32_16x16x32_bf16(a, b, acc, 0, 0, 0);
    }
    #pragma unroll
    for (int r = 0; r < 4; ++r) hred[wave][lane][r] = acc[r];
    __syncthreads();
    if (wave == 0) {
        #pragma unroll
        for (int r = 0; r < 4; ++r) {
            float v = hred[0][lane][r] + hred[1][lane][r] + hred[2][lane][r] + hred[3][lane][r];
            v += bmu[r16];
            v = 1.0f / (1.0f + expf(-v));
            out[(size_t)(tm * 16 + quad * 4 + r) * N_ACT + r16] = v;
        }
    }
}

extern "C" void kernel_launch(void* const* d_in, const int* in_sizes, int n_in,
                              void* d_out, int out_size, void* d_ws, size_t ws_size,
                              hipStream_t stream) {
    const float* x    = (const float*)d_in[0];
    const int*   ei   = (const int*)d_in[1];
    const int*   agent= (const int*)d_in[2];
    const float* Wgcn = (const float*)d_in[3];
    const float* bgcn = (const float*)d_in[4];
    const float* W1   = (const float*)d_in[5];
    const float* b1   = (const float*)d_in[6];
    const float* g1   = (const float*)d_in[7];
    const float* be1  = (const float*)d_in[8];
    const float* W2   = (const float*)d_in[9];
    const float* b2   = (const float*)d_in[10];
    const float* g2   = (const float*)d_in[11];
    const float* be2  = (const float*)d_in[12];
    const float* Wmu  = (const float*)d_in[13];
    const float* bmu  = (const float*)d_in[14];
    float* out = (float*)d_out;

    const int* srcp = ei;
    const int* dstp = ei + N_EDGES;

    // workspace layout (256B aligned). ONE contiguous zero region: nid | bcnt
    char* ws = (char*)d_ws;
    size_t off = 0;
    char* zero_base = ws;
    int* nid  = (int*)(ws + off);      off += ((size_t)N_NODES * 4 + 255) & ~(size_t)255;
    int* bcnt = (int*)(ws + off);      off += ((size_t)N_BUCKETS * 4 + 255) & ~(size_t)255;
    size_t zero_bytes = off;
    int* deg  = (int*)(ws + off);      off += ((size_t)N_NODES * 4 + 255) & ~(size_t)255;
    unsigned long long* pairbuf = (unsigned long long*)(ws + off);
    off += ((size_t)N_BUCKETS * BUCKET_CAP * 8 + 255) & ~(size_t)255;
    int* ebuf = (int*)(ws + off);      off += ((size_t)N_AGENTS * EB_STRIDE * 4 + 255) & ~(size_t)255;
    unsigned short* wgcn_t = (unsigned short*)(ws + off); off += ((size_t)IN_DIM * HID * 2 + 255) & ~(size_t)255;
    unsigned short* w1_t   = (unsigned short*)(ws + off); off += ((size_t)HID * FC1 * 2 + 255) & ~(size_t)255;
    unsigned short* w2_t   = (unsigned short*)(ws + off); off += ((size_t)FC1 * FC2 * 2 + 255) & ~(size_t)255;
    unsigned short* wmu_t  = (unsigned short*)(ws + off); off += ((size_t)FC2 * N_ACT * 2 + 255) & ~(size_t)255;
    unsigned short* agg    = (unsigned short*)(ws + off); off += ((size_t)N_AGENTS * IN_DIM * 2 + 255) & ~(size_t)255;
    unsigned short* h_node = (unsigned short*)(ws + off); off += ((size_t)N_AGENTS * HID * 2 + 255) & ~(size_t)255;
    unsigned short* zb  = (unsigned short*)(ws + off);    off += ((size_t)N_AGENTS * FC1 * 2 + 255) & ~(size_t)255;
    unsigned short* zbn = (unsigned short*)(ws + off);    off += ((size_t)N_AGENTS * FC1 * 2 + 255) & ~(size_t)255;
    unsigned short* zb2 = (unsigned short*)(ws + off);    off += ((size_t)N_AGENTS * FC2 * 2 + 255) & ~(size_t)255;

    // ---- single zero-init memset (nid | bcnt) ----
    hipMemsetAsync(zero_base, 0, zero_bytes, stream);

    // ---- scatter edges into buckets; tail blocks: weight transpose + claim ----
    scat_k<<<SCAT_BLOCKS + WTR_BLOCKS + CLAIM_BLOCKS, 256, 0, stream>>>(
        srcp, dstp, agent, nid, bcnt, pairbuf,
        Wgcn, W1, W2, Wmu, wgcn_t, w1_t, w2_t, wmu_t);

    // ---- per-bucket deg count (LDS) + claimed ebuf fill ----
    bucket_k<<<N_BUCKETS, 256, 0, stream>>>(bcnt, pairbuf, nid, deg, ebuf);

    // ---- aggregate raw x per agent slot (one wave per row) ----
    accumx_k<<<N_AGENTS / 4, 256, 0, stream>>>(agent, nid, deg, ebuf, x, agg);

    // ---- GCN layer: h_node = relu(agg @ Wgcn + bgcn) ----
    gemm_gcn_k<<<(HID / 128) * (N_AGENTS / 64), 256, 0, stream>>>(agg, wgcn_t, bgcn, h_node);

    // ---- FC1 (gather fused) + bias -> zb (raw) ----
    gemm_fc1_k<<<(FC1 / BN) * (N_AGENTS / BM), 256, 0, stream>>>(h_node, agent, nid, w1_t, b1, zb);

    // ---- LN1 + affine + ReLU -> zbn ----
    ln1_k<<<N_AGENTS / 4, 256, 0, stream>>>(zb, g1, be1, zbn);

    // ---- FC2 (128x128, clean GEMM) -> zb2 ----
    gemm_fc2_k<<<(FC2 / 128) * (N_AGENTS / 128), 256, 0, stream>>>(zbn, w2_t, b2, zb2);

    // ---- LN2 + ReLU + head ----
    ln2head_k<<<N_AGENTS / 16, 256, 0, stream>>>(zb2, g2, be2, wmu_t, bmu, out);
}